// Round 11
// baseline (421.325 us; speedup 1.0000x reference)
//
#include <hip/hip_runtime.h>
#include <hip/hip_bf16.h>
#include <stdint.h>

#define N_NODES 100000
#define N_EDGES 1600000
#define IN_DIM 128
#define HID_DIM 256
#define OUT_DIM 512
#define NBUK 391         // ceil(N_NODES / 256)
#define BCAP 8192        // slots per bucket region (expected max ~4400)
#define EPB 2048         // edges per k_bucket block

typedef __attribute__((ext_vector_type(4))) float f32x4;
typedef __attribute__((ext_vector_type(8))) short bf16x8;

__device__ __forceinline__ float bf16lo(uint32_t u){ uint32_t b = u << 16; return __builtin_bit_cast(float, b); }
__device__ __forceinline__ float bf16hi(uint32_t u){ uint32_t b = u & 0xffff0000u; return __builtin_bit_cast(float, b); }
__device__ __forceinline__ uint16_t f32_to_bf16(float f){
  uint32_t u = __builtin_bit_cast(uint32_t, f);
  uint32_t r = (u + 0x7fffu + ((u >> 16) & 1u)) >> 16;
  return (uint16_t)r;
}
__device__ __forceinline__ uint32_t pack_bf16_exact(float lo, float hi){
  return (__builtin_bit_cast(uint32_t, hi) & 0xffff0000u) | (__builtin_bit_cast(uint32_t, lo) >> 16);
}
__device__ __forceinline__ uint32_t pack_bf16_rne(float lo, float hi){
  return (uint32_t)f32_to_bf16(lo) | ((uint32_t)f32_to_bf16(hi) << 16);
}
__device__ __forceinline__ void gl2lds16(const void* g, void* l){
  __builtin_amdgcn_global_load_lds(
      (const __attribute__((address_space(1))) uint32_t*)g,
      (__attribute__((address_space(3))) uint32_t*)l, 16, 0, 0);
}

// ---------------- convert x to bf16 compact (+ init gcur/sum/sumsq) ----------
__global__ void k_convx(const float* __restrict__ x, uint16_t* __restrict__ X1x,
                        int* __restrict__ gcur, float* __restrict__ sum,
                        float* __restrict__ sumsq){
  if (blockIdx.x == 12500){
    const int t = threadIdx.x;
    for (int i = t; i < NBUK; i += 256) gcur[i] = i << 13;   // BCAP = 8192
    sum[t] = 0.f; sumsq[t] = 0.f;
    return;
  }
  const int idx = blockIdx.x * 256 + threadIdx.x;   // n*32 + q
  const int n = idx >> 5, q = idx & 31;
  const float4 v = *(const float4*)(x + (long)n * 128 + q * 4);
  ushort4 o;
  o.x = f32_to_bf16(v.x); o.y = f32_to_bf16(v.y);
  o.z = f32_to_bf16(v.z); o.w = f32_to_bf16(v.w);
  *(ushort4*)(X1x + (long)n * 128 + q * 4) = o;
}

// ---------------- CSR build (bucketed, no global scatter) ----------------
__global__ void k_bucket(const int* __restrict__ src, const int* __restrict__ dst,
                         int* __restrict__ gcur, int* __restrict__ ebuk){
  __shared__ int hist[NBUK], curs[NBUK], base[NBUK];
  const int tid = threadIdx.x;
  const int e0 = blockIdx.x * EPB;
  for (int t = tid; t < NBUK; t += 256) hist[t] = 0;
  __syncthreads();
  for (int i = 0; i < EPB; i += 256){
    int e = e0 + i + tid;
    if (e < N_EDGES) atomicAdd(&hist[dst[e] >> 8], 1);
  }
  __syncthreads();
  for (int t = tid; t < NBUK; t += 256){
    int h = hist[t];
    base[t] = h ? atomicAdd(&gcur[t], h) : 0;
    curs[t] = 0;
  }
  __syncthreads();
  for (int i = 0; i < EPB; i += 256){
    int e = e0 + i + tid;
    if (e < N_EDGES){
      int d = dst[e];
      int b = d >> 8;
      int idx = atomicAdd(&curs[b], 1);
      int pos = base[b] + idx;
      if (pos < ((b + 1) << 13))                 // capacity guard (never hit for this input)
        ebuk[pos] = ((d & 255) << 17) | src[e];  // src < 2^17
    }
  }
}

// one block per bucket: computes its own base (reduction over gcur), builds
// row_start slice + compacted esrc with LDS cursors.
__global__ __launch_bounds__(256)
void k_fillc(const int* __restrict__ gcur, const int* __restrict__ ebuk,
             int* __restrict__ row_start, int* __restrict__ esrc){
  __shared__ int ebuf[BCAP];
  __shared__ int cnt[256];
  __shared__ int wtot[4];
  __shared__ int red[4];
  const int b = blockIdx.x, tid = threadIdx.x, lane = tid & 63, wv = tid >> 6;
  const int nodebase = b << 8;
  const int nodecnt = min(256, N_NODES - nodebase);
  // bucket base = sum_{t<b} size_t
  int accb = 0;
  for (int t = tid; t < b; t += 256) accb += gcur[t] - (t << 13);
  #pragma unroll
  for (int d = 32; d > 0; d >>= 1) accb += __shfl_xor(accb, d);
  if (lane == 0) red[wv] = accb;
  int size_b = gcur[b] - (b << 13);
  if (size_b > BCAP) size_b = BCAP;
  cnt[tid] = 0;
  for (int i = tid; i < size_b; i += 256) ebuf[i] = ebuk[(b << 13) + i];
  __syncthreads();
  const int bs = red[0] + red[1] + red[2] + red[3];
  for (int i = tid; i < size_b; i += 256) atomicAdd(&cnt[ebuf[i] >> 17], 1);
  __syncthreads();
  // exclusive scan of cnt[256]
  const int c = cnt[tid];
  int v = c;
  #pragma unroll
  for (int d = 1; d < 64; d <<= 1){ int t = __shfl_up(v, d); if (lane >= d) v += t; }
  if (lane == 63) wtot[wv] = v;
  __syncthreads();
  if (tid < 4){
    int t = wtot[tid];
    #pragma unroll
    for (int d = 1; d < 4; d <<= 1){ int u = __shfl_up(t, d); if (tid >= d) t += u; }
    wtot[tid] = t;
  }
  __syncthreads();
  const int excl = (wv ? wtot[wv - 1] : 0) + (v - c);
  if (tid < nodecnt) row_start[nodebase + tid] = bs + excl;
  if (b == NBUK - 1 && tid == 0) row_start[N_NODES] = N_EDGES;
  cnt[tid] = excl;   // reuse as cursor
  __syncthreads();
  for (int i = tid; i < size_b; i += 256){
    int p = ebuf[i];
    int pos = atomicAdd(&cnt[p >> 17], 1);
    esrc[bs + pos] = p & 0x1FFFF;
  }
}

// ---------------- weight prep ----------------
__global__ void k_w1(const float* __restrict__ W1l, const float* __restrict__ W1r,
                     uint16_t* __restrict__ W1cat){
  int idx = blockIdx.x * 256 + threadIdx.x;   // 65536 = 256x256
  int j = idx >> 8, k = idx & 255;
  float v = (k < 128) ? W1l[j * 128 + k] : W1r[j * 128 + (k - 128)];
  W1cat[idx] = f32_to_bf16(v);
}

// fused BN-coef + W2 fold (each block recomputes scale/shift into LDS; block 0
// publishes them for k_agg2)
__global__ void k_w2(const float* __restrict__ W2l, const float* __restrict__ W2r,
                     const float* __restrict__ b2, const float* __restrict__ sum,
                     const float* __restrict__ sumsq, const float* __restrict__ gamma,
                     const float* __restrict__ beta, uint16_t* __restrict__ W2cat,
                     float* __restrict__ bias2, float* __restrict__ scale_g,
                     float* __restrict__ shift_g){
  __shared__ float sc_s[256], sh_s[256];
  const int tid = threadIdx.x;
  {
    const float inv_n = 1.0f / (float)N_NODES;
    float mean = sum[tid] * inv_n;
    float var = sumsq[tid] * inv_n - mean * mean;
    float sc = gamma[tid] * rsqrtf(var + 1e-5f);
    float sh = beta[tid] - mean * sc;
    sc_s[tid] = sc; sh_s[tid] = sh;
    if (blockIdx.x == 0){ scale_g[tid] = sc; shift_g[tid] = sh; }
  }
  __syncthreads();
  const int wid = (blockIdx.x * 256 + tid) >> 6;
  const int lane = tid & 63;
  float part = 0.f;
  #pragma unroll
  for (int t = 0; t < 4; t++){
    int k = t * 64 + lane;
    float wl = W2l[(long)wid * 256 + k];
    W2cat[(long)wid * 512 + k] = f32_to_bf16(wl);
    float wr = W2r[(long)wid * 256 + k];
    W2cat[(long)wid * 512 + 256 + k] = f32_to_bf16(wr * sc_s[k]);
    part += sh_s[k] * wr;
  }
  #pragma unroll
  for (int d = 32; d > 0; d >>= 1) part += __shfl_xor(part, d);
  if (lane == 0) bias2[wid] = b2[wid] + part;
}

// ---------------- aggregation (max) ----------------
__global__ void k_agg1(const uint32_t* __restrict__ X1x, const int* __restrict__ row_start,
                       const int* __restrict__ esrc, uint32_t* __restrict__ X1agg){
  const int wid = (blockIdx.x * 256 + threadIdx.x) >> 6;
  const int lane = threadIdx.x & 63;
  if (wid >= N_NODES) return;
  const int grp = lane >> 4, li = lane & 15;
  const int s0 = row_start[wid], s1 = row_start[wid + 1];
  float m[8];
  #pragma unroll
  for (int j = 0; j < 8; j++) m[j] = -INFINITY;

  #define ACC1(u)                                        \
    m[0] = fmaxf(m[0], bf16lo(u.x)); m[1] = fmaxf(m[1], bf16hi(u.x)); \
    m[2] = fmaxf(m[2], bf16lo(u.y)); m[3] = fmaxf(m[3], bf16hi(u.y)); \
    m[4] = fmaxf(m[4], bf16lo(u.z)); m[5] = fmaxf(m[5], bf16hi(u.z)); \
    m[6] = fmaxf(m[6], bf16lo(u.w)); m[7] = fmaxf(m[7], bf16hi(u.w));

  int e = s0 + grp;
  for (; e + 12 < s1; e += 16){
    const uint4 ua = *(const uint4*)(X1x + (long)esrc[e] * 64 + li * 4);
    const uint4 ub = *(const uint4*)(X1x + (long)esrc[e + 4] * 64 + li * 4);
    const uint4 uc = *(const uint4*)(X1x + (long)esrc[e + 8] * 64 + li * 4);
    const uint4 ud = *(const uint4*)(X1x + (long)esrc[e + 12] * 64 + li * 4);
    ACC1(ua); ACC1(ub); ACC1(uc); ACC1(ud);
  }
  for (; e < s1; e += 4){
    const uint4 u = *(const uint4*)(X1x + (long)esrc[e] * 64 + li * 4);
    ACC1(u);
  }
  #undef ACC1
  #pragma unroll
  for (int j = 0; j < 8; j++){
    m[j] = fmaxf(m[j], __shfl_xor(m[j], 16));
    m[j] = fmaxf(m[j], __shfl_xor(m[j], 32));
  }
  if (grp == 0){
    uint4 o;
    if (s1 == s0){ o.x = o.y = o.z = o.w = 0u; }
    else {
      o.x = pack_bf16_exact(m[0], m[1]);
      o.y = pack_bf16_exact(m[2], m[3]);
      o.z = pack_bf16_exact(m[4], m[5]);
      o.w = pack_bf16_exact(m[6], m[7]);
    }
    *(uint4*)(X1agg + (long)wid * 64 + li * 4) = o;
  }
}

__global__ void k_agg2(const uint32_t* __restrict__ X2h, const int* __restrict__ row_start,
                       const int* __restrict__ esrc, const float* __restrict__ scale,
                       const float* __restrict__ shift, uint32_t* __restrict__ X2agg){
  const int wid = (blockIdx.x * 256 + threadIdx.x) >> 6;
  const int lane = threadIdx.x & 63;
  if (wid >= N_NODES) return;
  const int half = lane >> 5, li = lane & 31;
  const int c0 = li * 8;
  const float4 sca = *(const float4*)(scale + c0);
  const float4 scb = *(const float4*)(scale + c0 + 4);
  const float4 sha = *(const float4*)(shift + c0);
  const float4 shb = *(const float4*)(shift + c0 + 4);
  const int s0 = row_start[wid], s1 = row_start[wid + 1];
  float m[8];
  #pragma unroll
  for (int j = 0; j < 8; j++) m[j] = -INFINITY;

  #define ACC8(u)                                                   \
    m[0] = fmaxf(m[0], fmaf(bf16lo(u.x), sca.x, sha.x));            \
    m[1] = fmaxf(m[1], fmaf(bf16hi(u.x), sca.y, sha.y));            \
    m[2] = fmaxf(m[2], fmaf(bf16lo(u.y), sca.z, sha.z));            \
    m[3] = fmaxf(m[3], fmaf(bf16hi(u.y), sca.w, sha.w));            \
    m[4] = fmaxf(m[4], fmaf(bf16lo(u.z), scb.x, shb.x));            \
    m[5] = fmaxf(m[5], fmaf(bf16hi(u.z), scb.y, shb.y));            \
    m[6] = fmaxf(m[6], fmaf(bf16lo(u.w), scb.z, shb.z));            \
    m[7] = fmaxf(m[7], fmaf(bf16hi(u.w), scb.w, shb.w));

  int e = s0 + half;
  for (; e + 6 < s1; e += 8){
    const uint4 ua = *(const uint4*)(X2h + (long)esrc[e] * 128 + li * 4);
    const uint4 ub = *(const uint4*)(X2h + (long)esrc[e + 2] * 128 + li * 4);
    const uint4 uc = *(const uint4*)(X2h + (long)esrc[e + 4] * 128 + li * 4);
    const uint4 ud = *(const uint4*)(X2h + (long)esrc[e + 6] * 128 + li * 4);
    ACC8(ua); ACC8(ub); ACC8(uc); ACC8(ud);
  }
  for (; e < s1; e += 2){
    const uint4 u = *(const uint4*)(X2h + (long)esrc[e] * 128 + li * 4);
    ACC8(u);
  }
  #undef ACC8
  #pragma unroll
  for (int j = 0; j < 8; j++) m[j] = fmaxf(m[j], __shfl_xor(m[j], 32));
  if (half == 0){
    uint4 o;
    if (s1 == s0){ o.x = 0u; o.y = 0u; o.z = 0u; o.w = 0u; }
    else {
      o.x = pack_bf16_rne(m[0], m[1]);
      o.y = pack_bf16_rne(m[2], m[3]);
      o.z = pack_bf16_rne(m[4], m[5]);
      o.w = pack_bf16_rne(m[6], m[7]);
    }
    *(uint4*)(X2agg + (long)wid * 128 + li * 4) = o;
  }
}

// ---------------- GEMM: C[M,NT] = [Alo|Ahi][M,KT] * B[NT,KT]^T (+bias) --------
// 256x256 tile, 512 threads (8 waves, 2m x 4n; wave tile 128x64), BK=64.
// Doubles FLOP per LDS-staged byte vs 128^2 (the round-10 diagnosis: gemm is
// staging-bandwidth-bound, ~7 TB/s effective through L2/L3). Same proven sync
// structure: dbuf LDS (2x64KB) + counted vmcnt(8) + XCD swizzle + XOR-swizzled
// LDS rows for conflict-free ds_read_b128.
template<int KT, bool EPI1>
__global__ __launch_bounds__(512, 2)
void k_gemm(const uint16_t* __restrict__ Alo, const uint16_t* __restrict__ Ahi,
            const uint16_t* __restrict__ B, const float* __restrict__ bias,
            uint16_t* __restrict__ outb, float* __restrict__ outf,
            float* __restrict__ sum, float* __restrict__ sumsq)
{
  constexpr int NSTEPS = KT / 64;
  constexpr int HSTEPS = NSTEPS / 2;
  constexpr int NT = EPI1 ? 256 : 512;
  constexpr int NW = NT / 256;                 // nblk count (1 or 2)
  constexpr int MT = 391;                      // ceil(N_NODES/256)
  constexpr int WG = MT * NW;
  constexpr int PER = (WG + 7) / 8;            // wgids per XCD (grid = PER*8)
  __shared__ uint8_t lds[2][65536];            // per buf: A 32K | B 32K
  const int bid = blockIdx.x;
  const int wgid = (bid & 7) * PER + (bid >> 3);
  if (wgid >= WG) return;
  const int mblk = wgid / NW, nblk = wgid % NW;
  const int tid = threadIdx.x, lane = tid & 63, wv = tid >> 6;
  const int wvm = wv >> 2, wvn = wv & 3;       // 2 x 4 wave grid

  f32x4 acc[8][4] = {};

  // staging: call i covers rows i*64 + (tid>>3); 16B per thread per call.
  const int srow = tid >> 3;                   // 0..63 (+ i*64)
  const int skb  = (tid & 7) * 16;
  const int kbsw = skb ^ ((srow & 7) << 4);    // srow&7 == row&7 for all i

  const uint8_t* asrc_lo[4];
  const uint8_t* asrc_hi[4];
  const uint8_t* bsrc[4];
  #pragma unroll
  for (int i = 0; i < 4; i++){
    long grow = (long)mblk * 256 + i * 64 + srow;
    if (grow > N_NODES - 1) grow = N_NODES - 1;
    asrc_lo[i] = (const uint8_t*)Alo + grow * KT + kbsw;
    asrc_hi[i] = (const uint8_t*)Ahi + grow * KT + kbsw;
    bsrc[i] = (const uint8_t*)B + ((long)nblk * 256 + i * 64 + srow) * (KT * 2) + kbsw;
  }

  #define STAGE(ks, buf)                                                       \
    {                                                                          \
      const long aoff = (ks) < HSTEPS ? (long)(ks) * 128 : -1;                 \
      _Pragma("unroll")                                                        \
      for (int i = 0; i < 4; i++)                                              \
        gl2lds16((ks) < HSTEPS ? asrc_lo[i] + (long)(ks) * 128                 \
                               : asrc_hi[i] + (long)((ks) - HSTEPS) * 128,     \
                 &lds[buf][i * 8192 + tid * 16]);                              \
      _Pragma("unroll")                                                        \
      for (int i = 0; i < 4; i++)                                              \
        gl2lds16(bsrc[i] + (long)(ks) * 128,                                   \
                 &lds[buf][32768 + i * 8192 + tid * 16]);                      \
      (void)aoff;                                                              \
    }

  STAGE(0, 0);

  #pragma unroll
  for (int ks = 0; ks < NSTEPS; ++ks){
    const int cur = ks & 1;
    if (ks + 1 < NSTEPS){
      STAGE(ks + 1, cur ^ 1);
      asm volatile("s_waitcnt vmcnt(8)" ::: "memory");
    } else {
      asm volatile("s_waitcnt vmcnt(0)" ::: "memory");
    }
    __builtin_amdgcn_s_barrier();
    asm volatile("" ::: "memory");

    const uint8_t* ldsA = &lds[cur][0];
    const uint8_t* ldsB = &lds[cur][32768];
    #pragma unroll
    for (int kk = 0; kk < 2; kk++){
      const int kb = kk * 64 + (lane >> 4) * 16;
      bf16x8 af[8], bfr[4];
      #pragma unroll
      for (int m = 0; m < 8; m++){
        int row = wvm * 128 + m * 16 + (lane & 15);
        af[m] = *(const bf16x8*)(ldsA + row * 128 + (kb ^ ((row & 7) << 4)));
      }
      #pragma unroll
      for (int n = 0; n < 4; n++){
        int row = wvn * 64 + n * 16 + (lane & 15);
        bfr[n] = *(const bf16x8*)(ldsB + row * 128 + (kb ^ ((row & 7) << 4)));
      }
      #pragma unroll
      for (int m = 0; m < 8; m++)
        #pragma unroll
        for (int n = 0; n < 4; n++)
          acc[m][n] = __builtin_amdgcn_mfma_f32_16x16x32_bf16(af[m], bfr[n], acc[m][n], 0, 0, 0);
    }

    asm volatile("" ::: "memory");
    __builtin_amdgcn_s_barrier();
    asm volatile("" ::: "memory");
  }
  #undef STAGE

  // epilogue
  const int rgrp = (lane >> 4) * 4;
  #pragma unroll
  for (int n = 0; n < 4; n++){
    const int col = nblk * 256 + wvn * 64 + n * 16 + (lane & 15);
    const float bv = bias[col];
    float s1v = 0.f, s2v = 0.f;
    #pragma unroll
    for (int m = 0; m < 8; m++){
      const int rowb = mblk * 256 + wvm * 128 + m * 16 + rgrp;
      f32x4 v = acc[m][n];
      #pragma unroll
      for (int j = 0; j < 4; j++){
        const int row = rowb + j;
        const float h = v[j] + bv;
        if (row < N_NODES){
          if (EPI1){
            outb[(long)row * NT + col] = f32_to_bf16(h);
            s1v += h; s2v += h * h;
          } else {
            __builtin_nontemporal_store(h, &outf[(long)row * NT + col]);
          }
        }
      }
    }
    if (EPI1){
      s1v += __shfl_xor(s1v, 16); s1v += __shfl_xor(s1v, 32);
      s2v += __shfl_xor(s2v, 16); s2v += __shfl_xor(s2v, 32);
      if (lane < 16){
        atomicAdd(&sum[col], s1v);
        atomicAdd(&sumsq[col], s2v);
      }
    }
  }
}

extern "C" void kernel_launch(void* const* d_in, const int* in_sizes, int n_in,
                              void* d_out, int out_size, void* d_ws, size_t ws_size,
                              hipStream_t stream){
  const float* x     = (const float*)d_in[0];
  const int*   ei    = (const int*)d_in[1];
  const float* W1l   = (const float*)d_in[2];
  const float* b1    = (const float*)d_in[3];
  const float* W1r   = (const float*)d_in[4];
  const float* gamma = (const float*)d_in[5];
  const float* beta  = (const float*)d_in[6];
  const float* W2l   = (const float*)d_in[7];
  const float* b2    = (const float*)d_in[8];
  const float* W2r   = (const float*)d_in[9];
  const int* esrc_in = ei;            // row 0 = src
  const int* edst_in = ei + N_EDGES;  // row 1 = dst

  uint8_t* ws = (uint8_t*)d_ws;
  uint16_t* X1agg    = (uint16_t*)(ws + 0);           // [N][128] bf16 agg1   25,600,000
  uint16_t* X1x      = (uint16_t*)(ws + 25600000);    // [N][128] bf16 x      25,600,000
  uint16_t* X2agg    = (uint16_t*)(ws + 51200000);    // [N][256] bf16 agg2   51,200,000
  uint16_t* X2h      = (uint16_t*)(ws + 102400000);   // [N][256] bf16 h_pre  51,200,000
  int* ebuk          = (int*)(ws + 51200000);         // aliases X2agg (CSR done before agg2)
  int* esrc          = (int*)(ws + 153600000);        // 6,400,000
  int* row_start     = (int*)(ws + 160000000);        // 400,128
  int* gcur          = (int*)(ws + 160402176);        // 1,564 (bucket cursors, 391)
  uint16_t* W1cat    = (uint16_t*)(ws + 160800256);   // 131,072
  uint16_t* W2cat    = (uint16_t*)(ws + 160931328);   // 524,288
  float* bias2       = (float*)(ws + 161455616);      // 2,048
  float* sum         = (float*)(ws + 161457664);      // 1,024
  float* sumsq       = (float*)(ws + 161458688);      // 1,024
  float* scale       = (float*)(ws + 161459712);      // 1,024
  float* shift       = (float*)(ws + 161460736);      // 1,024

  hipLaunchKernelGGL(k_convx, dim3(12501), dim3(256), 0, stream, x, X1x, gcur, sum, sumsq);
  hipLaunchKernelGGL(k_bucket, dim3(N_EDGES / EPB + 1), dim3(256), 0, stream,
                     esrc_in, edst_in, gcur, ebuk);
  hipLaunchKernelGGL(k_fillc, dim3(NBUK), dim3(256), 0, stream,
                     gcur, ebuk, row_start, esrc);

  hipLaunchKernelGGL(k_w1, dim3(256), dim3(256), 0, stream, W1l, W1r, W1cat);
  hipLaunchKernelGGL(k_agg1, dim3(25000), dim3(256), 0, stream,
                     (const uint32_t*)X1x, row_start, esrc, (uint32_t*)X1agg);

  // gemm1: WG=391 -> grid 392 (49 per XCD), 512 threads
  hipLaunchKernelGGL((k_gemm<256, true>), dim3(392), dim3(512), 0, stream,
                     X1agg, X1x, W1cat, b1, X2h, (float*)nullptr, sum, sumsq);

  hipLaunchKernelGGL(k_w2, dim3(128), dim3(256), 0, stream,
                     W2l, W2r, b2, sum, sumsq, gamma, beta, W2cat, bias2, scale, shift);

  hipLaunchKernelGGL(k_agg2, dim3(25000), dim3(256), 0, stream,
                     (const uint32_t*)X2h, row_start, esrc, scale, shift, (uint32_t*)X2agg);

  // gemm2: WG=782 -> grid 784 (98 per XCD), 512 threads
  hipLaunchKernelGGL((k_gemm<512, false>), dim3(784), dim3(512), 0, stream,
                     X2agg, X2h, W2cat, bias2, (uint16_t*)nullptr, (float*)d_out,
                     (float*)nullptr, (float*)nullptr);
}

// Round 12
// 410.959 us; speedup vs baseline: 1.0252x; 1.0252x over previous
//
#include <hip/hip_runtime.h>
#include <hip/hip_bf16.h>
#include <stdint.h>

#define N_NODES 100000
#define N_EDGES 1600000
#define IN_DIM 128
#define HID_DIM 256
#define OUT_DIM 512
#define NBUK 391         // ceil(N_NODES / 256)
#define BCAP 8192        // slots per bucket region (expected max ~4400)
#define EPB 2048         // edges per k_bucket block

typedef __attribute__((ext_vector_type(4))) float f32x4;
typedef __attribute__((ext_vector_type(8))) short bf16x8;

__device__ __forceinline__ float bf16lo(uint32_t u){ uint32_t b = u << 16; return __builtin_bit_cast(float, b); }
__device__ __forceinline__ float bf16hi(uint32_t u){ uint32_t b = u & 0xffff0000u; return __builtin_bit_cast(float, b); }
__device__ __forceinline__ uint16_t f32_to_bf16(float f){
  uint32_t u = __builtin_bit_cast(uint32_t, f);
  uint32_t r = (u + 0x7fffu + ((u >> 16) & 1u)) >> 16;
  return (uint16_t)r;
}
__device__ __forceinline__ uint32_t pack_bf16_exact(float lo, float hi){
  return (__builtin_bit_cast(uint32_t, hi) & 0xffff0000u) | (__builtin_bit_cast(uint32_t, lo) >> 16);
}
__device__ __forceinline__ uint32_t pack_bf16_rne(float lo, float hi){
  return (uint32_t)f32_to_bf16(lo) | ((uint32_t)f32_to_bf16(hi) << 16);
}
__device__ __forceinline__ void gl2lds16(const void* g, void* l){
  __builtin_amdgcn_global_load_lds(
      (const __attribute__((address_space(1))) uint32_t*)g,
      (__attribute__((address_space(3))) uint32_t*)l, 16, 0, 0);
}

// ---------------- convert x to bf16 compact (+ init gcur/sum/sumsq) ----------
__global__ void k_convx(const float* __restrict__ x, uint16_t* __restrict__ X1x,
                        int* __restrict__ gcur, float* __restrict__ sum,
                        float* __restrict__ sumsq){
  if (blockIdx.x == 12500){
    const int t = threadIdx.x;
    for (int i = t; i < NBUK; i += 256) gcur[i] = i << 13;   // BCAP = 8192
    sum[t] = 0.f; sumsq[t] = 0.f;
    return;
  }
  const int idx = blockIdx.x * 256 + threadIdx.x;   // n*32 + q
  const int n = idx >> 5, q = idx & 31;
  const float4 v = *(const float4*)(x + (long)n * 128 + q * 4);
  ushort4 o;
  o.x = f32_to_bf16(v.x); o.y = f32_to_bf16(v.y);
  o.z = f32_to_bf16(v.z); o.w = f32_to_bf16(v.w);
  *(ushort4*)(X1x + (long)n * 128 + q * 4) = o;
}

// ---------------- CSR build (bucketed, no global scatter) ----------------
__global__ void k_bucket(const int* __restrict__ src, const int* __restrict__ dst,
                         int* __restrict__ gcur, int* __restrict__ ebuk){
  __shared__ int hist[NBUK], curs[NBUK], base[NBUK];
  const int tid = threadIdx.x;
  const int e0 = blockIdx.x * EPB;
  for (int t = tid; t < NBUK; t += 256) hist[t] = 0;
  __syncthreads();
  for (int i = 0; i < EPB; i += 256){
    int e = e0 + i + tid;
    if (e < N_EDGES) atomicAdd(&hist[dst[e] >> 8], 1);
  }
  __syncthreads();
  for (int t = tid; t < NBUK; t += 256){
    int h = hist[t];
    base[t] = h ? atomicAdd(&gcur[t], h) : 0;
    curs[t] = 0;
  }
  __syncthreads();
  for (int i = 0; i < EPB; i += 256){
    int e = e0 + i + tid;
    if (e < N_EDGES){
      int d = dst[e];
      int b = d >> 8;
      int idx = atomicAdd(&curs[b], 1);
      int pos = base[b] + idx;
      if (pos < ((b + 1) << 13))                 // capacity guard (never hit for this input)
        ebuk[pos] = ((d & 255) << 17) | src[e];  // src < 2^17
    }
  }
}

// one block per bucket: computes its own base (reduction over gcur), builds
// row_start slice + compacted esrc with LDS cursors.
__global__ __launch_bounds__(256)
void k_fillc(const int* __restrict__ gcur, const int* __restrict__ ebuk,
             int* __restrict__ row_start, int* __restrict__ esrc){
  __shared__ int ebuf[BCAP];
  __shared__ int cnt[256];
  __shared__ int wtot[4];
  __shared__ int red[4];
  const int b = blockIdx.x, tid = threadIdx.x, lane = tid & 63, wv = tid >> 6;
  const int nodebase = b << 8;
  const int nodecnt = min(256, N_NODES - nodebase);
  // bucket base = sum_{t<b} size_t
  int accb = 0;
  for (int t = tid; t < b; t += 256) accb += gcur[t] - (t << 13);
  #pragma unroll
  for (int d = 32; d > 0; d >>= 1) accb += __shfl_xor(accb, d);
  if (lane == 0) red[wv] = accb;
  int size_b = gcur[b] - (b << 13);
  if (size_b > BCAP) size_b = BCAP;
  cnt[tid] = 0;
  for (int i = tid; i < size_b; i += 256) ebuf[i] = ebuk[(b << 13) + i];
  __syncthreads();
  const int bs = red[0] + red[1] + red[2] + red[3];
  for (int i = tid; i < size_b; i += 256) atomicAdd(&cnt[ebuf[i] >> 17], 1);
  __syncthreads();
  // exclusive scan of cnt[256]
  const int c = cnt[tid];
  int v = c;
  #pragma unroll
  for (int d = 1; d < 64; d <<= 1){ int t = __shfl_up(v, d); if (lane >= d) v += t; }
  if (lane == 63) wtot[wv] = v;
  __syncthreads();
  if (tid < 4){
    int t = wtot[tid];
    #pragma unroll
    for (int d = 1; d < 4; d <<= 1){ int u = __shfl_up(t, d); if (tid >= d) t += u; }
    wtot[tid] = t;
  }
  __syncthreads();
  const int excl = (wv ? wtot[wv - 1] : 0) + (v - c);
  if (tid < nodecnt) row_start[nodebase + tid] = bs + excl;
  if (b == NBUK - 1 && tid == 0) row_start[N_NODES] = N_EDGES;
  cnt[tid] = excl;   // reuse as cursor
  __syncthreads();
  for (int i = tid; i < size_b; i += 256){
    int p = ebuf[i];
    int pos = atomicAdd(&cnt[p >> 17], 1);
    esrc[bs + pos] = p & 0x1FFFF;
  }
}

// ---------------- weight prep ----------------
__global__ void k_w1(const float* __restrict__ W1l, const float* __restrict__ W1r,
                     uint16_t* __restrict__ W1cat){
  int idx = blockIdx.x * 256 + threadIdx.x;   // 65536 = 256x256
  int j = idx >> 8, k = idx & 255;
  float v = (k < 128) ? W1l[j * 128 + k] : W1r[j * 128 + (k - 128)];
  W1cat[idx] = f32_to_bf16(v);
}

// fused BN-coef + W2 fold (each block recomputes scale/shift into LDS; block 0
// publishes them for k_agg2)
__global__ void k_w2(const float* __restrict__ W2l, const float* __restrict__ W2r,
                     const float* __restrict__ b2, const float* __restrict__ sum,
                     const float* __restrict__ sumsq, const float* __restrict__ gamma,
                     const float* __restrict__ beta, uint16_t* __restrict__ W2cat,
                     float* __restrict__ bias2, float* __restrict__ scale_g,
                     float* __restrict__ shift_g){
  __shared__ float sc_s[256], sh_s[256];
  const int tid = threadIdx.x;
  {
    const float inv_n = 1.0f / (float)N_NODES;
    float mean = sum[tid] * inv_n;
    float var = sumsq[tid] * inv_n - mean * mean;
    float sc = gamma[tid] * rsqrtf(var + 1e-5f);
    float sh = beta[tid] - mean * sc;
    sc_s[tid] = sc; sh_s[tid] = sh;
    if (blockIdx.x == 0){ scale_g[tid] = sc; shift_g[tid] = sh; }
  }
  __syncthreads();
  const int wid = (blockIdx.x * 256 + tid) >> 6;
  const int lane = tid & 63;
  float part = 0.f;
  #pragma unroll
  for (int t = 0; t < 4; t++){
    int k = t * 64 + lane;
    float wl = W2l[(long)wid * 256 + k];
    W2cat[(long)wid * 512 + k] = f32_to_bf16(wl);
    float wr = W2r[(long)wid * 256 + k];
    W2cat[(long)wid * 512 + 256 + k] = f32_to_bf16(wr * sc_s[k]);
    part += sh_s[k] * wr;
  }
  #pragma unroll
  for (int d = 32; d > 0; d >>= 1) part += __shfl_xor(part, d);
  if (lane == 0) bias2[wid] = b2[wid] + part;
}

// ---------------- aggregation (max) ----------------
__global__ void k_agg1(const uint32_t* __restrict__ X1x, const int* __restrict__ row_start,
                       const int* __restrict__ esrc, uint32_t* __restrict__ X1agg){
  const int wid = (blockIdx.x * 256 + threadIdx.x) >> 6;
  const int lane = threadIdx.x & 63;
  if (wid >= N_NODES) return;
  const int grp = lane >> 4, li = lane & 15;
  const int s0 = row_start[wid], s1 = row_start[wid + 1];
  float m[8];
  #pragma unroll
  for (int j = 0; j < 8; j++) m[j] = -INFINITY;

  #define ACC1(u)                                        \
    m[0] = fmaxf(m[0], bf16lo(u.x)); m[1] = fmaxf(m[1], bf16hi(u.x)); \
    m[2] = fmaxf(m[2], bf16lo(u.y)); m[3] = fmaxf(m[3], bf16hi(u.y)); \
    m[4] = fmaxf(m[4], bf16lo(u.z)); m[5] = fmaxf(m[5], bf16hi(u.z)); \
    m[6] = fmaxf(m[6], bf16lo(u.w)); m[7] = fmaxf(m[7], bf16hi(u.w));

  int e = s0 + grp;
  for (; e + 12 < s1; e += 16){
    const uint4 ua = *(const uint4*)(X1x + (long)esrc[e] * 64 + li * 4);
    const uint4 ub = *(const uint4*)(X1x + (long)esrc[e + 4] * 64 + li * 4);
    const uint4 uc = *(const uint4*)(X1x + (long)esrc[e + 8] * 64 + li * 4);
    const uint4 ud = *(const uint4*)(X1x + (long)esrc[e + 12] * 64 + li * 4);
    ACC1(ua); ACC1(ub); ACC1(uc); ACC1(ud);
  }
  for (; e < s1; e += 4){
    const uint4 u = *(const uint4*)(X1x + (long)esrc[e] * 64 + li * 4);
    ACC1(u);
  }
  #undef ACC1
  #pragma unroll
  for (int j = 0; j < 8; j++){
    m[j] = fmaxf(m[j], __shfl_xor(m[j], 16));
    m[j] = fmaxf(m[j], __shfl_xor(m[j], 32));
  }
  if (grp == 0){
    uint4 o;
    if (s1 == s0){ o.x = o.y = o.z = o.w = 0u; }
    else {
      o.x = pack_bf16_exact(m[0], m[1]);
      o.y = pack_bf16_exact(m[2], m[3]);
      o.z = pack_bf16_exact(m[4], m[5]);
      o.w = pack_bf16_exact(m[6], m[7]);
    }
    *(uint4*)(X1agg + (long)wid * 64 + li * 4) = o;
  }
}

__global__ void k_agg2(const uint32_t* __restrict__ X2h, const int* __restrict__ row_start,
                       const int* __restrict__ esrc, const float* __restrict__ scale,
                       const float* __restrict__ shift, uint32_t* __restrict__ X2agg){
  const int wid = (blockIdx.x * 256 + threadIdx.x) >> 6;
  const int lane = threadIdx.x & 63;
  if (wid >= N_NODES) return;
  const int half = lane >> 5, li = lane & 31;
  const int c0 = li * 8;
  const float4 sca = *(const float4*)(scale + c0);
  const float4 scb = *(const float4*)(scale + c0 + 4);
  const float4 sha = *(const float4*)(shift + c0);
  const float4 shb = *(const float4*)(shift + c0 + 4);
  const int s0 = row_start[wid], s1 = row_start[wid + 1];
  float m[8];
  #pragma unroll
  for (int j = 0; j < 8; j++) m[j] = -INFINITY;

  #define ACC8(u)                                                   \
    m[0] = fmaxf(m[0], fmaf(bf16lo(u.x), sca.x, sha.x));            \
    m[1] = fmaxf(m[1], fmaf(bf16hi(u.x), sca.y, sha.y));            \
    m[2] = fmaxf(m[2], fmaf(bf16lo(u.y), sca.z, sha.z));            \
    m[3] = fmaxf(m[3], fmaf(bf16hi(u.y), sca.w, sha.w));            \
    m[4] = fmaxf(m[4], fmaf(bf16lo(u.z), scb.x, shb.x));            \
    m[5] = fmaxf(m[5], fmaf(bf16hi(u.z), scb.y, shb.y));            \
    m[6] = fmaxf(m[6], fmaf(bf16lo(u.w), scb.z, shb.z));            \
    m[7] = fmaxf(m[7], fmaf(bf16hi(u.w), scb.w, shb.w));

  int e = s0 + half;
  for (; e + 6 < s1; e += 8){
    const uint4 ua = *(const uint4*)(X2h + (long)esrc[e] * 128 + li * 4);
    const uint4 ub = *(const uint4*)(X2h + (long)esrc[e + 2] * 128 + li * 4);
    const uint4 uc = *(const uint4*)(X2h + (long)esrc[e + 4] * 128 + li * 4);
    const uint4 ud = *(const uint4*)(X2h + (long)esrc[e + 6] * 128 + li * 4);
    ACC8(ua); ACC8(ub); ACC8(uc); ACC8(ud);
  }
  for (; e < s1; e += 2){
    const uint4 u = *(const uint4*)(X2h + (long)esrc[e] * 128 + li * 4);
    ACC8(u);
  }
  #undef ACC8
  #pragma unroll
  for (int j = 0; j < 8; j++) m[j] = fmaxf(m[j], __shfl_xor(m[j], 32));
  if (half == 0){
    uint4 o;
    if (s1 == s0){ o.x = 0u; o.y = 0u; o.z = 0u; o.w = 0u; }
    else {
      o.x = pack_bf16_rne(m[0], m[1]);
      o.y = pack_bf16_rne(m[2], m[3]);
      o.z = pack_bf16_rne(m[4], m[5]);
      o.w = pack_bf16_rne(m[6], m[7]);
    }
    *(uint4*)(X2agg + (long)wid * 128 + li * 4) = o;
  }
}

// ---------------- GEMM: C[M,NT] = [Alo|Ahi][M,KT] * B[NT,KT]^T (+bias) --------
// 128x128 tile, 4 waves (2x2), BK=32, 16x16x32 MFMA.
// DEPTH-2 staging pipeline (round-11 diagnosis: per-wave one-tile-deep vmcnt
// batches serialize at ~1 load-latency per K-step): 4-slot LDS ring
// (4 x 16KB = 64KB -> still 2 blocks/CU); STAGE(ks+2) issued each step,
// vmcnt(8) = 2 STAGEs (4 instr each) in flight -> 2 step-times of latency
// budget per batch. XCD-swizzled 1D grid. Source addresses pre-swizzled with
// 2-bit XOR ((row&3)<<4); ds_read applies the same involution.
template<int KT, bool EPI1>
__global__ __launch_bounds__(256, 2)
void k_gemm(const uint16_t* __restrict__ Alo, const uint16_t* __restrict__ Ahi,
            const uint16_t* __restrict__ B, const float* __restrict__ bias,
            uint16_t* __restrict__ outb, float* __restrict__ outf,
            float* __restrict__ sum, float* __restrict__ sumsq)
{
  constexpr int NSTEPS = KT / 32;
  constexpr int HSTEPS = NSTEPS / 2;
  constexpr int NT = EPI1 ? 256 : 512;
  constexpr int NW = NT / 128;                 // nblk count (2 or 4)
  constexpr int WG = 782 * NW;                 // real workgroups
  constexpr int PER = (WG + 7) / 8;            // wgids per XCD (grid padded to PER*8)
  __shared__ uint8_t lds[4][16384];            // ring slot: A 8K | B 8K
  const int bid = blockIdx.x;
  const int wgid = (bid & 7) * PER + (bid >> 3);
  if (wgid >= WG) return;
  const int mblk = wgid / NW, nblk = wgid % NW;
  const int tid = threadIdx.x, lane = tid & 63, wv = tid >> 6;
  const int wvm = wv >> 1, wvn = wv & 1;

  f32x4 acc[4][4] = {};

  // staging chunk mapping: chunk c = j*256 + tid (j=0,1), r = c>>2 (row),
  // q = c&3 (16B pos). Source pre-swizzled: kbs = q*16 ^ ((r&3)<<4).
  const int r0 = tid >> 2;                     // rows r0 and r0+64
  const int kbs = ((tid & 3) * 16) ^ ((r0 & 3) << 4);   // (r0+64)&3 == r0&3

  const uint8_t* a_lo[2];
  const uint8_t* a_hi[2];
  const uint8_t* b_src[2];
  #pragma unroll
  for (int j = 0; j < 2; j++){
    long grow = (long)mblk * 128 + j * 64 + r0;
    if (grow > N_NODES - 1) grow = N_NODES - 1;
    a_lo[j] = (const uint8_t*)Alo + grow * KT + kbs;     // lo half: row stride KT bytes
    a_hi[j] = (const uint8_t*)Ahi + grow * KT + kbs;
    b_src[j] = (const uint8_t*)B + ((long)nblk * 128 + j * 64 + r0) * (KT * 2) + kbs;
  }

  // wave-uniform LDS dest bases (lane*16 appended by HW)
  #define STAGE(ks, slot)                                                      \
    {                                                                          \
      const long aoff = (ks) < HSTEPS ? (long)(ks) * 64 : (long)((ks) - HSTEPS) * 64; \
      const bool lo_ = (ks) < HSTEPS;                                          \
      _Pragma("unroll")                                                        \
      for (int j = 0; j < 2; j++)                                              \
        gl2lds16((lo_ ? a_lo[j] : a_hi[j]) + aoff,                             \
                 &lds[slot][j * 4096 + wv * 1024]);                            \
      _Pragma("unroll")                                                        \
      for (int j = 0; j < 2; j++)                                              \
        gl2lds16(b_src[j] + (long)(ks) * 64,                                   \
                 &lds[slot][8192 + j * 4096 + wv * 1024]);                     \
    }

  STAGE(0, 0);
  STAGE(1, 1);

  #pragma unroll
  for (int ks = 0; ks < NSTEPS; ++ks){
    const int cur = ks & 3;
    if (ks + 2 < NSTEPS){
      STAGE(ks + 2, (ks + 2) & 3);
      asm volatile("s_waitcnt vmcnt(8)" ::: "memory");
    } else if (ks + 2 == NSTEPS){
      asm volatile("s_waitcnt vmcnt(4)" ::: "memory");
    } else {
      asm volatile("s_waitcnt vmcnt(0)" ::: "memory");
    }
    __builtin_amdgcn_s_barrier();
    asm volatile("" ::: "memory");

    const uint8_t* ldsA = &lds[cur][0];
    const uint8_t* ldsB = &lds[cur][8192];
    const int kb = (lane >> 4) * 16;
    bf16x8 af[4], bfr[4];
    #pragma unroll
    for (int m = 0; m < 4; m++){
      int row = wvm * 64 + m * 16 + (lane & 15);
      af[m] = *(const bf16x8*)(ldsA + row * 64 + (kb ^ ((row & 3) << 4)));
    }
    #pragma unroll
    for (int n = 0; n < 4; n++){
      int row = wvn * 64 + n * 16 + (lane & 15);
      bfr[n] = *(const bf16x8*)(ldsB + row * 64 + (kb ^ ((row & 3) << 4)));
    }
    #pragma unroll
    for (int m = 0; m < 4; m++)
      #pragma unroll
      for (int n = 0; n < 4; n++)
        acc[m][n] = __builtin_amdgcn_mfma_f32_16x16x32_bf16(af[m], bfr[n], acc[m][n], 0, 0, 0);

    asm volatile("" ::: "memory");
    __builtin_amdgcn_s_barrier();
    asm volatile("" ::: "memory");
  }
  #undef STAGE

  // epilogue
  const int rgrp = (lane >> 4) * 4;
  #pragma unroll
  for (int n = 0; n < 4; n++){
    const int col = nblk * 128 + wvn * 64 + n * 16 + (lane & 15);
    const float bv = bias[col];
    float s1v = 0.f, s2v = 0.f;
    #pragma unroll
    for (int m = 0; m < 4; m++){
      const int rowb = mblk * 128 + wvm * 64 + m * 16 + rgrp;
      f32x4 v = acc[m][n];
      #pragma unroll
      for (int j = 0; j < 4; j++){
        const int row = rowb + j;
        const float h = v[j] + bv;
        if (row < N_NODES){
          if (EPI1){
            outb[(long)row * NT + col] = f32_to_bf16(h);
            s1v += h; s2v += h * h;
          } else {
            __builtin_nontemporal_store(h, &outf[(long)row * NT + col]);
          }
        }
      }
    }
    if (EPI1){
      s1v += __shfl_xor(s1v, 16); s1v += __shfl_xor(s1v, 32);
      s2v += __shfl_xor(s2v, 16); s2v += __shfl_xor(s2v, 32);
      if (lane < 16){
        atomicAdd(&sum[col], s1v);
        atomicAdd(&sumsq[col], s2v);
      }
    }
  }
}

extern "C" void kernel_launch(void* const* d_in, const int* in_sizes, int n_in,
                              void* d_out, int out_size, void* d_ws, size_t ws_size,
                              hipStream_t stream){
  const float* x     = (const float*)d_in[0];
  const int*   ei    = (const int*)d_in[1];
  const float* W1l   = (const float*)d_in[2];
  const float* b1    = (const float*)d_in[3];
  const float* W1r   = (const float*)d_in[4];
  const float* gamma = (const float*)d_in[5];
  const float* beta  = (const float*)d_in[6];
  const float* W2l   = (const float*)d_in[7];
  const float* b2    = (const float*)d_in[8];
  const float* W2r   = (const float*)d_in[9];
  const int* esrc_in = ei;            // row 0 = src
  const int* edst_in = ei + N_EDGES;  // row 1 = dst

  uint8_t* ws = (uint8_t*)d_ws;
  uint16_t* X1agg    = (uint16_t*)(ws + 0);           // [N][128] bf16 agg1   25,600,000
  uint16_t* X1x      = (uint16_t*)(ws + 25600000);    // [N][128] bf16 x      25,600,000
  uint16_t* X2agg    = (uint16_t*)(ws + 51200000);    // [N][256] bf16 agg2   51,200,000
  uint16_t* X2h      = (uint16_t*)(ws + 102400000);   // [N][256] bf16 h_pre  51,200,000
  int* ebuk          = (int*)(ws + 51200000);         // aliases X2agg (CSR done before agg2)
  int* esrc          = (int*)(ws + 153600000);        // 6,400,000
  int* row_start     = (int*)(ws + 160000000);        // 400,128
  int* gcur          = (int*)(ws + 160402176);        // 1,564 (bucket cursors, 391)
  uint16_t* W1cat    = (uint16_t*)(ws + 160800256);   // 131,072
  uint16_t* W2cat    = (uint16_t*)(ws + 160931328);   // 524,288
  float* bias2       = (float*)(ws + 161455616);      // 2,048
  float* sum         = (float*)(ws + 161457664);      // 1,024
  float* sumsq       = (float*)(ws + 161458688);      // 1,024
  float* scale       = (float*)(ws + 161459712);      // 1,024
  float* shift       = (float*)(ws + 161460736);      // 1,024

  hipLaunchKernelGGL(k_convx, dim3(12501), dim3(256), 0, stream, x, X1x, gcur, sum, sumsq);
  hipLaunchKernelGGL(k_bucket, dim3(N_EDGES / EPB + 1), dim3(256), 0, stream,
                     esrc_in, edst_in, gcur, ebuk);
  hipLaunchKernelGGL(k_fillc, dim3(NBUK), dim3(256), 0, stream,
                     gcur, ebuk, row_start, esrc);

  hipLaunchKernelGGL(k_w1, dim3(256), dim3(256), 0, stream, W1l, W1r, W1cat);
  hipLaunchKernelGGL(k_agg1, dim3(25000), dim3(256), 0, stream,
                     (const uint32_t*)X1x, row_start, esrc, (uint32_t*)X1agg);

  // gemm1: WG=1564 -> grid 1568 (196 per XCD)
  hipLaunchKernelGGL((k_gemm<256, true>), dim3(1568), dim3(256), 0, stream,
                     X1agg, X1x, W1cat, b1, X2h, (float*)nullptr, sum, sumsq);

  hipLaunchKernelGGL(k_w2, dim3(128), dim3(256), 0, stream,
                     W2l, W2r, b2, sum, sumsq, gamma, beta, W2cat, bias2, scale, shift);

  hipLaunchKernelGGL(k_agg2, dim3(25000), dim3(256), 0, stream,
                     (const uint32_t*)X2h, row_start, esrc, scale, shift, (uint32_t*)X2agg);

  // gemm2: WG=3128 -> grid 3128 (391 per XCD)
  hipLaunchKernelGGL((k_gemm<512, false>), dim3(3128), dim3(256), 0, stream,
                     X2agg, X2h, W2cat, bias2, (uint16_t*)nullptr, (float*)d_out,
                     (float*)nullptr, (float*)nullptr);
}

// Round 15
// 393.224 us; speedup vs baseline: 1.0715x; 1.0451x over previous
//
#include <hip/hip_runtime.h>
#include <hip/hip_bf16.h>
#include <stdint.h>

#define N_NODES 100000
#define N_EDGES 1600000
#define IN_DIM 128
#define HID_DIM 256
#define OUT_DIM 512
#define NBUK 391         // ceil(N_NODES / 256)
#define BCAP 8192        // slots per bucket region (expected max ~4400)
#define EPB 2048         // edges per k_bucket block

typedef __attribute__((ext_vector_type(4))) float f32x4;
typedef __attribute__((ext_vector_type(8))) short bf16x8;

__device__ __forceinline__ float bf16lo(uint32_t u){ uint32_t b = u << 16; return __builtin_bit_cast(float, b); }
__device__ __forceinline__ float bf16hi(uint32_t u){ uint32_t b = u & 0xffff0000u; return __builtin_bit_cast(float, b); }
__device__ __forceinline__ uint16_t f32_to_bf16(float f){
  uint32_t u = __builtin_bit_cast(uint32_t, f);
  uint32_t r = (u + 0x7fffu + ((u >> 16) & 1u)) >> 16;
  return (uint16_t)r;
}
__device__ __forceinline__ uint32_t pack_bf16_exact(float lo, float hi){
  return (__builtin_bit_cast(uint32_t, hi) & 0xffff0000u) | (__builtin_bit_cast(uint32_t, lo) >> 16);
}
__device__ __forceinline__ uint32_t pack_bf16_rne(float lo, float hi){
  return (uint32_t)f32_to_bf16(lo) | ((uint32_t)f32_to_bf16(hi) << 16);
}
__device__ __forceinline__ void gl2lds16(const void* g, void* l){
  __builtin_amdgcn_global_load_lds(
      (const __attribute__((address_space(1))) uint32_t*)g,
      (__attribute__((address_space(3))) uint32_t*)l, 16, 0, 0);
}

// ---------------- convert x to bf16 compact (+ init gcur/sum/sumsq) ----------
__global__ void k_convx(const float* __restrict__ x, uint16_t* __restrict__ X1x,
                        int* __restrict__ gcur, float* __restrict__ sum,
                        float* __restrict__ sumsq){
  if (blockIdx.x == 12500){
    const int t = threadIdx.x;
    for (int i = t; i < NBUK; i += 256) gcur[i] = i << 13;   // BCAP = 8192
    sum[t] = 0.f; sumsq[t] = 0.f;
    return;
  }
  const int idx = blockIdx.x * 256 + threadIdx.x;   // n*32 + q
  const int n = idx >> 5, q = idx & 31;
  const float4 v = *(const float4*)(x + (long)n * 128 + q * 4);
  ushort4 o;
  o.x = f32_to_bf16(v.x); o.y = f32_to_bf16(v.y);
  o.z = f32_to_bf16(v.z); o.w = f32_to_bf16(v.w);
  *(ushort4*)(X1x + (long)n * 128 + q * 4) = o;
}

// ---------------- CSR build (bucketed, no global scatter) ----------------
__global__ void k_bucket(const int* __restrict__ src, const int* __restrict__ dst,
                         int* __restrict__ gcur, int* __restrict__ ebuk){
  __shared__ int hist[NBUK], curs[NBUK], base[NBUK];
  const int tid = threadIdx.x;
  const int e0 = blockIdx.x * EPB;
  for (int t = tid; t < NBUK; t += 256) hist[t] = 0;
  __syncthreads();
  for (int i = 0; i < EPB; i += 256){
    int e = e0 + i + tid;
    if (e < N_EDGES) atomicAdd(&hist[dst[e] >> 8], 1);
  }
  __syncthreads();
  for (int t = tid; t < NBUK; t += 256){
    int h = hist[t];
    base[t] = h ? atomicAdd(&gcur[t], h) : 0;
    curs[t] = 0;
  }
  __syncthreads();
  for (int i = 0; i < EPB; i += 256){
    int e = e0 + i + tid;
    if (e < N_EDGES){
      int d = dst[e];
      int b = d >> 8;
      int idx = atomicAdd(&curs[b], 1);
      int pos = base[b] + idx;
      if (pos < ((b + 1) << 13))                 // capacity guard (never hit for this input)
        ebuk[pos] = ((d & 255) << 17) | src[e];  // src < 2^17
    }
  }
}

// one block per bucket: computes its own base (reduction over gcur), builds
// row_start slice + compacted esrc with LDS cursors.
__global__ __launch_bounds__(256)
void k_fillc(const int* __restrict__ gcur, const int* __restrict__ ebuk,
             int* __restrict__ row_start, int* __restrict__ esrc){
  __shared__ int ebuf[BCAP];
  __shared__ int cnt[256];
  __shared__ int wtot[4];
  __shared__ int red[4];
  const int b = blockIdx.x, tid = threadIdx.x, lane = tid & 63, wv = tid >> 6;
  const int nodebase = b << 8;
  const int nodecnt = min(256, N_NODES - nodebase);
  // bucket base = sum_{t<b} size_t
  int accb = 0;
  for (int t = tid; t < b; t += 256) accb += gcur[t] - (t << 13);
  #pragma unroll
  for (int d = 32; d > 0; d >>= 1) accb += __shfl_xor(accb, d);
  if (lane == 0) red[wv] = accb;
  int size_b = gcur[b] - (b << 13);
  if (size_b > BCAP) size_b = BCAP;
  cnt[tid] = 0;
  for (int i = tid; i < size_b; i += 256) ebuf[i] = ebuk[(b << 13) + i];
  __syncthreads();
  const int bs = red[0] + red[1] + red[2] + red[3];
  for (int i = tid; i < size_b; i += 256) atomicAdd(&cnt[ebuf[i] >> 17], 1);
  __syncthreads();
  // exclusive scan of cnt[256]
  const int c = cnt[tid];
  int v = c;
  #pragma unroll
  for (int d = 1; d < 64; d <<= 1){ int t = __shfl_up(v, d); if (lane >= d) v += t; }
  if (lane == 63) wtot[wv] = v;
  __syncthreads();
  if (tid < 4){
    int t = wtot[tid];
    #pragma unroll
    for (int d = 1; d < 4; d <<= 1){ int u = __shfl_up(t, d); if (tid >= d) t += u; }
    wtot[tid] = t;
  }
  __syncthreads();
  const int excl = (wv ? wtot[wv - 1] : 0) + (v - c);
  if (tid < nodecnt) row_start[nodebase + tid] = bs + excl;
  if (b == NBUK - 1 && tid == 0) row_start[N_NODES] = N_EDGES;
  cnt[tid] = excl;   // reuse as cursor
  __syncthreads();
  for (int i = tid; i < size_b; i += 256){
    int p = ebuf[i];
    int pos = atomicAdd(&cnt[p >> 17], 1);
    esrc[bs + pos] = p & 0x1FFFF;
  }
}

// ---------------- weight prep ----------------
__global__ void k_w1(const float* __restrict__ W1l, const float* __restrict__ W1r,
                     uint16_t* __restrict__ W1cat){
  int idx = blockIdx.x * 256 + threadIdx.x;   // 65536 = 256x256
  int j = idx >> 8, k = idx & 255;
  float v = (k < 128) ? W1l[j * 128 + k] : W1r[j * 128 + (k - 128)];
  W1cat[idx] = f32_to_bf16(v);
}

// fused BN-coef + W2 fold (each block recomputes scale/shift into LDS; block 0
// publishes them for k_agg2)
__global__ void k_w2(const float* __restrict__ W2l, const float* __restrict__ W2r,
                     const float* __restrict__ b2, const float* __restrict__ sum,
                     const float* __restrict__ sumsq, const float* __restrict__ gamma,
                     const float* __restrict__ beta, uint16_t* __restrict__ W2cat,
                     float* __restrict__ bias2, float* __restrict__ scale_g,
                     float* __restrict__ shift_g){
  __shared__ float sc_s[256], sh_s[256];
  const int tid = threadIdx.x;
  {
    const float inv_n = 1.0f / (float)N_NODES;
    float mean = sum[tid] * inv_n;
    float var = sumsq[tid] * inv_n - mean * mean;
    float sc = gamma[tid] * rsqrtf(var + 1e-5f);
    float sh = beta[tid] - mean * sc;
    sc_s[tid] = sc; sh_s[tid] = sh;
    if (blockIdx.x == 0){ scale_g[tid] = sc; shift_g[tid] = sh; }
  }
  __syncthreads();
  const int wid = (blockIdx.x * 256 + tid) >> 6;
  const int lane = tid & 63;
  float part = 0.f;
  #pragma unroll
  for (int t = 0; t < 4; t++){
    int k = t * 64 + lane;
    float wl = W2l[(long)wid * 256 + k];
    W2cat[(long)wid * 512 + k] = f32_to_bf16(wl);
    float wr = W2r[(long)wid * 256 + k];
    W2cat[(long)wid * 512 + 256 + k] = f32_to_bf16(wr * sc_s[k]);
    part += sh_s[k] * wr;
  }
  #pragma unroll
  for (int d = 32; d > 0; d >>= 1) part += __shfl_xor(part, d);
  if (lane == 0) bias2[wid] = b2[wid] + part;
}

// ---------------- aggregation (max) ----------------
__global__ void k_agg1(const uint32_t* __restrict__ X1x, const int* __restrict__ row_start,
                       const int* __restrict__ esrc, uint32_t* __restrict__ X1agg){
  const int wid = (blockIdx.x * 256 + threadIdx.x) >> 6;
  const int lane = threadIdx.x & 63;
  if (wid >= N_NODES) return;
  const int grp = lane >> 4, li = lane & 15;
  const int s0 = row_start[wid], s1 = row_start[wid + 1];
  float m[8];
  #pragma unroll
  for (int j = 0; j < 8; j++) m[j] = -INFINITY;

  #define ACC1(u)                                        \
    m[0] = fmaxf(m[0], bf16lo(u.x)); m[1] = fmaxf(m[1], bf16hi(u.x)); \
    m[2] = fmaxf(m[2], bf16lo(u.y)); m[3] = fmaxf(m[3], bf16hi(u.y)); \
    m[4] = fmaxf(m[4], bf16lo(u.z)); m[5] = fmaxf(m[5], bf16hi(u.z)); \
    m[6] = fmaxf(m[6], bf16lo(u.w)); m[7] = fmaxf(m[7], bf16hi(u.w));

  int e = s0 + grp;
  for (; e + 12 < s1; e += 16){
    const uint4 ua = *(const uint4*)(X1x + (long)esrc[e] * 64 + li * 4);
    const uint4 ub = *(const uint4*)(X1x + (long)esrc[e + 4] * 64 + li * 4);
    const uint4 uc = *(const uint4*)(X1x + (long)esrc[e + 8] * 64 + li * 4);
    const uint4 ud = *(const uint4*)(X1x + (long)esrc[e + 12] * 64 + li * 4);
    ACC1(ua); ACC1(ub); ACC1(uc); ACC1(ud);
  }
  for (; e < s1; e += 4){
    const uint4 u = *(const uint4*)(X1x + (long)esrc[e] * 64 + li * 4);
    ACC1(u);
  }
  #undef ACC1
  #pragma unroll
  for (int j = 0; j < 8; j++){
    m[j] = fmaxf(m[j], __shfl_xor(m[j], 16));
    m[j] = fmaxf(m[j], __shfl_xor(m[j], 32));
  }
  if (grp == 0){
    uint4 o;
    if (s1 == s0){ o.x = o.y = o.z = o.w = 0u; }
    else {
      o.x = pack_bf16_exact(m[0], m[1]);
      o.y = pack_bf16_exact(m[2], m[3]);
      o.z = pack_bf16_exact(m[4], m[5]);
      o.w = pack_bf16_exact(m[6], m[7]);
    }
    *(uint4*)(X1agg + (long)wid * 64 + li * 4) = o;
  }
}

__global__ void k_agg2(const uint32_t* __restrict__ X2h, const int* __restrict__ row_start,
                       const int* __restrict__ esrc, const float* __restrict__ scale,
                       const float* __restrict__ shift, uint32_t* __restrict__ X2agg){
  const int wid = (blockIdx.x * 256 + threadIdx.x) >> 6;
  const int lane = threadIdx.x & 63;
  if (wid >= N_NODES) return;
  const int half = lane >> 5, li = lane & 31;
  const int c0 = li * 8;
  const float4 sca = *(const float4*)(scale + c0);
  const float4 scb = *(const float4*)(scale + c0 + 4);
  const float4 sha = *(const float4*)(shift + c0);
  const float4 shb = *(const float4*)(shift + c0 + 4);
  const int s0 = row_start[wid], s1 = row_start[wid + 1];
  float m[8];
  #pragma unroll
  for (int j = 0; j < 8; j++) m[j] = -INFINITY;

  #define ACC8(u)                                                   \
    m[0] = fmaxf(m[0], fmaf(bf16lo(u.x), sca.x, sha.x));            \
    m[1] = fmaxf(m[1], fmaf(bf16hi(u.x), sca.y, sha.y));            \
    m[2] = fmaxf(m[2], fmaf(bf16lo(u.y), sca.z, sha.z));            \
    m[3] = fmaxf(m[3], fmaf(bf16hi(u.y), sca.w, sha.w));            \
    m[4] = fmaxf(m[4], fmaf(bf16lo(u.z), scb.x, shb.x));            \
    m[5] = fmaxf(m[5], fmaf(bf16hi(u.z), scb.y, shb.y));            \
    m[6] = fmaxf(m[6], fmaf(bf16lo(u.w), scb.z, shb.z));            \
    m[7] = fmaxf(m[7], fmaf(bf16hi(u.w), scb.w, shb.w));

  int e = s0 + half;
  for (; e + 6 < s1; e += 8){
    const uint4 ua = *(const uint4*)(X2h + (long)esrc[e] * 128 + li * 4);
    const uint4 ub = *(const uint4*)(X2h + (long)esrc[e + 2] * 128 + li * 4);
    const uint4 uc = *(const uint4*)(X2h + (long)esrc[e + 4] * 128 + li * 4);
    const uint4 ud = *(const uint4*)(X2h + (long)esrc[e + 6] * 128 + li * 4);
    ACC8(ua); ACC8(ub); ACC8(uc); ACC8(ud);
  }
  for (; e < s1; e += 2){
    const uint4 u = *(const uint4*)(X2h + (long)esrc[e] * 128 + li * 4);
    ACC8(u);
  }
  #undef ACC8
  #pragma unroll
  for (int j = 0; j < 8; j++) m[j] = fmaxf(m[j], __shfl_xor(m[j], 32));
  if (half == 0){
    uint4 o;
    if (s1 == s0){ o.x = 0u; o.y = 0u; o.z = 0u; o.w = 0u; }
    else {
      o.x = pack_bf16_rne(m[0], m[1]);
      o.y = pack_bf16_rne(m[2], m[3]);
      o.z = pack_bf16_rne(m[4], m[5]);
      o.w = pack_bf16_rne(m[6], m[7]);
    }
    *(uint4*)(X2agg + (long)wid * 128 + li * 4) = o;
  }
}

// ---------------- GEMM: C[M,NT] = [Alo|Ahi][M,KT] * B[NT,KT]^T (+bias) --------
// m97-replica / occupancy-first, RACE-SAFE: 128x128 tile, 4 waves, BK=64,
// SINGLE 32KB buffer (A 16K | B 16K), __syncthreads() on BOTH barrier sites
// (full vmcnt+lgkm drain -- rule #18: raw s_barrier lets sunk MFMAs/ds_reads
// cross, which raced in r14). __launch_bounds__(256,4) -> up to 4 blocks/CU
// (r8 measured 88 VGPR at this tile; LDS allows 5). Cross-block concurrency
// supplies overlap (m114). XCD-swizzled 1D grid; 3-bit XOR swizzle both-sides.
template<int KT, bool EPI1>
__global__ __launch_bounds__(256, 4)
void k_gemm(const uint16_t* __restrict__ Alo, const uint16_t* __restrict__ Ahi,
            const uint16_t* __restrict__ B, const float* __restrict__ bias,
            uint16_t* __restrict__ outb, float* __restrict__ outf,
            float* __restrict__ sum, float* __restrict__ sumsq)
{
  constexpr int NSTEPS = KT / 64;
  constexpr int HSTEPS = NSTEPS / 2;
  constexpr int NT = EPI1 ? 256 : 512;
  constexpr int NW = NT / 128;                 // nblk count (2 or 4)
  constexpr int WG = 782 * NW;                 // real workgroups
  constexpr int PER = (WG + 7) / 8;            // wgids per XCD (grid padded to PER*8)
  __shared__ uint8_t lds[32768];               // A 16K | B 16K (single buffer)
  const int bid = blockIdx.x;
  const int wgid = (bid & 7) * PER + (bid >> 3);
  if (wgid >= WG) return;
  const int mblk = wgid / NW, nblk = wgid % NW;
  const int tid = threadIdx.x, lane = tid & 63, wv = tid >> 6;
  const int wvm = wv >> 1, wvn = wv & 1;

  f32x4 acc[4][4] = {};

  const int srow = wv * 32 + (lane >> 3);   // + i*8
  const int skb  = (lane & 7) * 16;

  // per-lane global source addresses (row-clamped A); A halves: row stride KT bytes
  const uint8_t* asrc_lo[4];
  const uint8_t* asrc_hi[4];
  const uint8_t* bsrc[4];
  #pragma unroll
  for (int i = 0; i < 4; i++){
    int row = srow + i * 8;
    int kbsw = skb ^ ((row & 7) << 4);
    long grow = (long)mblk * 128 + row;
    if (grow > N_NODES - 1) grow = N_NODES - 1;
    asrc_lo[i] = (const uint8_t*)Alo + grow * KT + kbsw;
    asrc_hi[i] = (const uint8_t*)Ahi + grow * KT + kbsw;
    bsrc[i] = (const uint8_t*)B + ((long)nblk * 128 + row) * (KT * 2) + kbsw;
  }

  #define STAGE(ks)                                                          \
    _Pragma("unroll")                                                        \
    for (int i = 0; i < 4; i++)                                              \
      gl2lds16((ks) < HSTEPS ? asrc_lo[i] + (long)(ks) * 128                 \
                             : asrc_hi[i] + (long)((ks) - HSTEPS) * 128,     \
               &lds[(wv * 4 + i) * 1024]);                                   \
    _Pragma("unroll")                                                        \
    for (int i = 0; i < 4; i++)                                              \
      gl2lds16(bsrc[i] + (long)(ks) * 128,                                   \
               &lds[16384 + (wv * 4 + i) * 1024]);

  #pragma unroll
  for (int ks = 0; ks < NSTEPS; ++ks){
    if (ks) __syncthreads();   // full drain: all waves' LDS reads complete
    STAGE(ks);
    __syncthreads();           // full drain: vmcnt(0) -> staged data landed

    const uint8_t* ldsA = &lds[0];
    const uint8_t* ldsB = &lds[16384];
    #pragma unroll
    for (int kk = 0; kk < 2; kk++){
      const int kb = kk * 64 + (lane >> 4) * 16;
      bf16x8 af[4], bfr[4];
      #pragma unroll
      for (int m = 0; m < 4; m++){
        int row = wvm * 64 + m * 16 + (lane & 15);
        af[m] = *(const bf16x8*)(ldsA + row * 128 + (kb ^ ((row & 7) << 4)));
      }
      #pragma unroll
      for (int n = 0; n < 4; n++){
        int row = wvn * 64 + n * 16 + (lane & 15);
        bfr[n] = *(const bf16x8*)(ldsB + row * 128 + (kb ^ ((row & 7) << 4)));
      }
      #pragma unroll
      for (int m = 0; m < 4; m++)
        #pragma unroll
        for (int n = 0; n < 4; n++)
          acc[m][n] = __builtin_amdgcn_mfma_f32_16x16x32_bf16(af[m], bfr[n], acc[m][n], 0, 0, 0);
    }
  }
  #undef STAGE

  // epilogue
  const int rgrp = (lane >> 4) * 4;
  #pragma unroll
  for (int n = 0; n < 4; n++){
    const int col = nblk * 128 + wvn * 64 + n * 16 + (lane & 15);
    const float bv = bias[col];
    float s1v = 0.f, s2v = 0.f;
    #pragma unroll
    for (int m = 0; m < 4; m++){
      const int rowb = mblk * 128 + wvm * 64 + m * 16 + rgrp;
      f32x4 v = acc[m][n];
      #pragma unroll
      for (int j = 0; j < 4; j++){
        const int row = rowb + j;
        const float h = v[j] + bv;
        if (row < N_NODES){
          if (EPI1){
            outb[(long)row * NT + col] = f32_to_bf16(h);
            s1v += h; s2v += h * h;
          } else {
            __builtin_nontemporal_store(h, &outf[(long)row * NT + col]);
          }
        }
      }
    }
    if (EPI1){
      s1v += __shfl_xor(s1v, 16); s1v += __shfl_xor(s1v, 32);
      s2v += __shfl_xor(s2v, 16); s2v += __shfl_xor(s2v, 32);
      if (lane < 16){
        atomicAdd(&sum[col], s1v);
        atomicAdd(&sumsq[col], s2v);
      }
    }
  }
}

extern "C" void kernel_launch(void* const* d_in, const int* in_sizes, int n_in,
                              void* d_out, int out_size, void* d_ws, size_t ws_size,
                              hipStream_t stream){
  const float* x     = (const float*)d_in[0];
  const int*   ei    = (const int*)d_in[1];
  const float* W1l   = (const float*)d_in[2];
  const float* b1    = (const float*)d_in[3];
  const float* W1r   = (const float*)d_in[4];
  const float* gamma = (const float*)d_in[5];
  const float* beta  = (const float*)d_in[6];
  const float* W2l   = (const float*)d_in[7];
  const float* b2    = (const float*)d_in[8];
  const float* W2r   = (const float*)d_in[9];
  const int* esrc_in = ei;            // row 0 = src
  const int* edst_in = ei + N_EDGES;  // row 1 = dst

  uint8_t* ws = (uint8_t*)d_ws;
  uint16_t* X1agg    = (uint16_t*)(ws + 0);           // [N][128] bf16 agg1   25,600,000
  uint16_t* X1x      = (uint16_t*)(ws + 25600000);    // [N][128] bf16 x      25,600,000
  uint16_t* X2agg    = (uint16_t*)(ws + 51200000);    // [N][256] bf16 agg2   51,200,000
  uint16_t* X2h      = (uint16_t*)(ws + 102400000);   // [N][256] bf16 h_pre  51,200,000
  int* ebuk          = (int*)(ws + 51200000);         // aliases X2agg (CSR done before agg2)
  int* esrc          = (int*)(ws + 153600000);        // 6,400,000
  int* row_start     = (int*)(ws + 160000000);        // 400,128
  int* gcur          = (int*)(ws + 160402176);        // 1,564 (bucket cursors, 391)
  uint16_t* W1cat    = (uint16_t*)(ws + 160800256);   // 131,072
  uint16_t* W2cat    = (uint16_t*)(ws + 160931328);   // 524,288
  float* bias2       = (float*)(ws + 161455616);      // 2,048
  float* sum         = (float*)(ws + 161457664);      // 1,024
  float* sumsq       = (float*)(ws + 161458688);      // 1,024
  float* scale       = (float*)(ws + 161459712);      // 1,024
  float* shift       = (float*)(ws + 161460736);      // 1,024

  hipLaunchKernelGGL(k_convx, dim3(12501), dim3(256), 0, stream, x, X1x, gcur, sum, sumsq);
  hipLaunchKernelGGL(k_bucket, dim3(N_EDGES / EPB + 1), dim3(256), 0, stream,
                     esrc_in, edst_in, gcur, ebuk);
  hipLaunchKernelGGL(k_fillc, dim3(NBUK), dim3(256), 0, stream,
                     gcur, ebuk, row_start, esrc);

  hipLaunchKernelGGL(k_w1, dim3(256), dim3(256), 0, stream, W1l, W1r, W1cat);
  hipLaunchKernelGGL(k_agg1, dim3(25000), dim3(256), 0, stream,
                     (const uint32_t*)X1x, row_start, esrc, (uint32_t*)X1agg);

  // gemm1: WG=1564 -> grid 1568 (196 per XCD)
  hipLaunchKernelGGL((k_gemm<256, true>), dim3(1568), dim3(256), 0, stream,
                     X1agg, X1x, W1cat, b1, X2h, (float*)nullptr, sum, sumsq);

  hipLaunchKernelGGL(k_w2, dim3(128), dim3(256), 0, stream,
                     W2l, W2r, b2, sum, sumsq, gamma, beta, W2cat, bias2, scale, shift);

  hipLaunchKernelGGL(k_agg2, dim3(25000), dim3(256), 0, stream,
                     (const uint32_t*)X2h, row_start, esrc, scale, shift, (uint32_t*)X2agg);

  // gemm2: WG=3128 -> grid 3128 (391 per XCD)
  hipLaunchKernelGGL((k_gemm<512, false>), dim3(3128), dim3(256), 0, stream,
                     X2agg, X2h, W2cat, bias2, (uint16_t*)nullptr, (float*)d_out,
                     (float*)nullptr, (float*)nullptr);
}

// Round 16
// 389.521 us; speedup vs baseline: 1.0816x; 1.0095x over previous
//
#include <hip/hip_runtime.h>
#include <hip/hip_bf16.h>
#include <stdint.h>

#define N_NODES 100000
#define N_EDGES 1600000
#define IN_DIM 128
#define HID_DIM 256
#define OUT_DIM 512
#define NBUK 391         // ceil(N_NODES / 256)
#define BCAP 8192        // slots per bucket region (expected max ~4400)
#define EPB 2048         // edges per k_bucket block

typedef __attribute__((ext_vector_type(4))) float f32x4;
typedef __attribute__((ext_vector_type(8))) short bf16x8;

__device__ __forceinline__ float bf16lo(uint32_t u){ uint32_t b = u << 16; return __builtin_bit_cast(float, b); }
__device__ __forceinline__ float bf16hi(uint32_t u){ uint32_t b = u & 0xffff0000u; return __builtin_bit_cast(float, b); }
__device__ __forceinline__ uint16_t f32_to_bf16(float f){
  uint32_t u = __builtin_bit_cast(uint32_t, f);
  uint32_t r = (u + 0x7fffu + ((u >> 16) & 1u)) >> 16;
  return (uint16_t)r;
}
__device__ __forceinline__ uint32_t pack_bf16_exact(float lo, float hi){
  return (__builtin_bit_cast(uint32_t, hi) & 0xffff0000u) | (__builtin_bit_cast(uint32_t, lo) >> 16);
}
__device__ __forceinline__ uint32_t pack_bf16_rne(float lo, float hi){
  return (uint32_t)f32_to_bf16(lo) | ((uint32_t)f32_to_bf16(hi) << 16);
}
__device__ __forceinline__ void gl2lds16(const void* g, void* l){
  __builtin_amdgcn_global_load_lds(
      (const __attribute__((address_space(1))) uint32_t*)g,
      (__attribute__((address_space(3))) uint32_t*)l, 16, 0, 0);
}

// -------- k_pre: convx (bid<12500) | init (bid==12500) | w1 (bid>12500) ------
// All three parts are mutually independent -> one launch.
__global__ void k_pre(const float* __restrict__ x, uint16_t* __restrict__ X1x,
                      int* __restrict__ gcur, float* __restrict__ sum,
                      float* __restrict__ sumsq, const float* __restrict__ W1l,
                      const float* __restrict__ W1r, uint16_t* __restrict__ W1cat){
  const int bid = blockIdx.x, tid = threadIdx.x;
  if (bid < 12500){
    const int idx = bid * 256 + tid;   // n*32 + q
    const int n = idx >> 5, q = idx & 31;
    const float4 v = *(const float4*)(x + (long)n * 128 + q * 4);
    ushort4 o;
    o.x = f32_to_bf16(v.x); o.y = f32_to_bf16(v.y);
    o.z = f32_to_bf16(v.z); o.w = f32_to_bf16(v.w);
    *(ushort4*)(X1x + (long)n * 128 + q * 4) = o;
  } else if (bid == 12500){
    for (int i = tid; i < NBUK; i += 256) gcur[i] = i << 13;   // BCAP = 8192
    sum[tid] = 0.f; sumsq[tid] = 0.f;
  } else {
    const int idx = (bid - 12501) * 256 + tid;   // 65536 = 256x256
    const int j = idx >> 8, k = idx & 255;
    float v = (k < 128) ? W1l[j * 128 + k] : W1r[j * 128 + (k - 128)];
    W1cat[idx] = f32_to_bf16(v);
  }
}

// ---------------- CSR build (bucketed, no global scatter) ----------------
__global__ void k_bucket(const int* __restrict__ src, const int* __restrict__ dst,
                         int* __restrict__ gcur, int* __restrict__ ebuk){
  __shared__ int hist[NBUK], curs[NBUK], base[NBUK];
  const int tid = threadIdx.x;
  const int e0 = blockIdx.x * EPB;
  for (int t = tid; t < NBUK; t += 256) hist[t] = 0;
  __syncthreads();
  for (int i = 0; i < EPB; i += 256){
    int e = e0 + i + tid;
    if (e < N_EDGES) atomicAdd(&hist[dst[e] >> 8], 1);
  }
  __syncthreads();
  for (int t = tid; t < NBUK; t += 256){
    int h = hist[t];
    base[t] = h ? atomicAdd(&gcur[t], h) : 0;
    curs[t] = 0;
  }
  __syncthreads();
  for (int i = 0; i < EPB; i += 256){
    int e = e0 + i + tid;
    if (e < N_EDGES){
      int d = dst[e];
      int b = d >> 8;
      int idx = atomicAdd(&curs[b], 1);
      int pos = base[b] + idx;
      if (pos < ((b + 1) << 13))                 // capacity guard (never hit for this input)
        ebuk[pos] = ((d & 255) << 17) | src[e];  // src < 2^17
    }
  }
}

// one block per bucket: computes its own base (reduction over gcur), builds
// row_start slice + compacted esrc with LDS cursors.
__global__ __launch_bounds__(256)
void k_fillc(const int* __restrict__ gcur, const int* __restrict__ ebuk,
             int* __restrict__ row_start, int* __restrict__ esrc){
  __shared__ int ebuf[BCAP];
  __shared__ int cnt[256];
  __shared__ int wtot[4];
  __shared__ int red[4];
  const int b = blockIdx.x, tid = threadIdx.x, lane = tid & 63, wv = tid >> 6;
  const int nodebase = b << 8;
  const int nodecnt = min(256, N_NODES - nodebase);
  // bucket base = sum_{t<b} size_t
  int accb = 0;
  for (int t = tid; t < b; t += 256) accb += gcur[t] - (t << 13);
  #pragma unroll
  for (int d = 32; d > 0; d >>= 1) accb += __shfl_xor(accb, d);
  if (lane == 0) red[wv] = accb;
  int size_b = gcur[b] - (b << 13);
  if (size_b > BCAP) size_b = BCAP;
  cnt[tid] = 0;
  for (int i = tid; i < size_b; i += 256) ebuf[i] = ebuk[(b << 13) + i];
  __syncthreads();
  const int bs = red[0] + red[1] + red[2] + red[3];
  for (int i = tid; i < size_b; i += 256) atomicAdd(&cnt[ebuf[i] >> 17], 1);
  __syncthreads();
  // exclusive scan of cnt[256]
  const int c = cnt[tid];
  int v = c;
  #pragma unroll
  for (int d = 1; d < 64; d <<= 1){ int t = __shfl_up(v, d); if (lane >= d) v += t; }
  if (lane == 63) wtot[wv] = v;
  __syncthreads();
  if (tid < 4){
    int t = wtot[tid];
    #pragma unroll
    for (int d = 1; d < 4; d <<= 1){ int u = __shfl_up(t, d); if (tid >= d) t += u; }
    wtot[tid] = t;
  }
  __syncthreads();
  const int excl = (wv ? wtot[wv - 1] : 0) + (v - c);
  if (tid < nodecnt) row_start[nodebase + tid] = bs + excl;
  if (b == NBUK - 1 && tid == 0) row_start[N_NODES] = N_EDGES;
  cnt[tid] = excl;   // reuse as cursor
  __syncthreads();
  for (int i = tid; i < size_b; i += 256){
    int p = ebuf[i];
    int pos = atomicAdd(&cnt[p >> 17], 1);
    esrc[bs + pos] = p & 0x1FFFF;
  }
}

// ---------------- aggregation (max) ----------------
__global__ void k_agg1(const uint32_t* __restrict__ X1x, const int* __restrict__ row_start,
                       const int* __restrict__ esrc, uint32_t* __restrict__ X1agg){
  const int wid = (blockIdx.x * 256 + threadIdx.x) >> 6;
  const int lane = threadIdx.x & 63;
  if (wid >= N_NODES) return;
  const int grp = lane >> 4, li = lane & 15;
  const int s0 = row_start[wid], s1 = row_start[wid + 1];
  float m[8];
  #pragma unroll
  for (int j = 0; j < 8; j++) m[j] = -INFINITY;

  #define ACC1(u)                                        \
    m[0] = fmaxf(m[0], bf16lo(u.x)); m[1] = fmaxf(m[1], bf16hi(u.x)); \
    m[2] = fmaxf(m[2], bf16lo(u.y)); m[3] = fmaxf(m[3], bf16hi(u.y)); \
    m[4] = fmaxf(m[4], bf16lo(u.z)); m[5] = fmaxf(m[5], bf16hi(u.z)); \
    m[6] = fmaxf(m[6], bf16lo(u.w)); m[7] = fmaxf(m[7], bf16hi(u.w));

  int e = s0 + grp;
  for (; e + 12 < s1; e += 16){
    const uint4 ua = *(const uint4*)(X1x + (long)esrc[e] * 64 + li * 4);
    const uint4 ub = *(const uint4*)(X1x + (long)esrc[e + 4] * 64 + li * 4);
    const uint4 uc = *(const uint4*)(X1x + (long)esrc[e + 8] * 64 + li * 4);
    const uint4 ud = *(const uint4*)(X1x + (long)esrc[e + 12] * 64 + li * 4);
    ACC1(ua); ACC1(ub); ACC1(uc); ACC1(ud);
  }
  for (; e < s1; e += 4){
    const uint4 u = *(const uint4*)(X1x + (long)esrc[e] * 64 + li * 4);
    ACC1(u);
  }
  #undef ACC1
  #pragma unroll
  for (int j = 0; j < 8; j++){
    m[j] = fmaxf(m[j], __shfl_xor(m[j], 16));
    m[j] = fmaxf(m[j], __shfl_xor(m[j], 32));
  }
  if (grp == 0){
    uint4 o;
    if (s1 == s0){ o.x = o.y = o.z = o.w = 0u; }
    else {
      o.x = pack_bf16_exact(m[0], m[1]);
      o.y = pack_bf16_exact(m[2], m[3]);
      o.z = pack_bf16_exact(m[4], m[5]);
      o.w = pack_bf16_exact(m[6], m[7]);
    }
    *(uint4*)(X1agg + (long)wid * 64 + li * 4) = o;
  }
}

// -------- k_aggw2: agg2 (bid<25000) | w2 fold (bid>=25000) -------------------
// Both parts depend only on gemm1 outputs (X2h, sum, sumsq) -> one launch.
// Each block recomputes BN scale/shift from sum/sumsq into LDS (cheap, 256ch).
__global__ void k_aggw2(const uint32_t* __restrict__ X2h, const int* __restrict__ row_start,
                        const int* __restrict__ esrc, const float* __restrict__ sum,
                        const float* __restrict__ sumsq, const float* __restrict__ gamma,
                        const float* __restrict__ beta, uint32_t* __restrict__ X2agg,
                        const float* __restrict__ W2l, const float* __restrict__ W2r,
                        const float* __restrict__ b2, uint16_t* __restrict__ W2cat,
                        float* __restrict__ bias2){
  __shared__ float sc_s[256], sh_s[256];
  const int bid = blockIdx.x, tid = threadIdx.x;
  {
    const float inv_n = 1.0f / (float)N_NODES;
    float mean = sum[tid] * inv_n;
    float var = sumsq[tid] * inv_n - mean * mean;
    float sc = gamma[tid] * rsqrtf(var + 1e-5f);
    sc_s[tid] = sc;
    sh_s[tid] = beta[tid] - mean * sc;
  }
  __syncthreads();

  if (bid >= 25000){
    // ---- w2: fold BN into W2r columns + bias ----
    const int wid = ((bid - 25000) * 256 + tid) >> 6;
    const int lane = tid & 63;
    float part = 0.f;
    #pragma unroll
    for (int t = 0; t < 4; t++){
      int k = t * 64 + lane;
      float wl = W2l[(long)wid * 256 + k];
      W2cat[(long)wid * 512 + k] = f32_to_bf16(wl);
      float wr = W2r[(long)wid * 256 + k];
      W2cat[(long)wid * 512 + 256 + k] = f32_to_bf16(wr * sc_s[k]);
      part += sh_s[k] * wr;
    }
    #pragma unroll
    for (int d = 32; d > 0; d >>= 1) part += __shfl_xor(part, d);
    if (lane == 0) bias2[wid] = b2[wid] + part;
    return;
  }

  // ---- agg2: wave per dst node, 2x 32-lane halves, BN inline, 4-deep ----
  const int wid = (bid * 256 + tid) >> 6;
  const int lane = tid & 63;
  const int half = lane >> 5, li = lane & 31;
  const int c0 = li * 8;
  const float4 sca = *(const float4*)(sc_s + c0);
  const float4 scb = *(const float4*)(sc_s + c0 + 4);
  const float4 sha = *(const float4*)(sh_s + c0);
  const float4 shb = *(const float4*)(sh_s + c0 + 4);
  const int s0 = row_start[wid], s1 = row_start[wid + 1];
  float m[8];
  #pragma unroll
  for (int j = 0; j < 8; j++) m[j] = -INFINITY;

  #define ACC8(u)                                                   \
    m[0] = fmaxf(m[0], fmaf(bf16lo(u.x), sca.x, sha.x));            \
    m[1] = fmaxf(m[1], fmaf(bf16hi(u.x), sca.y, sha.y));            \
    m[2] = fmaxf(m[2], fmaf(bf16lo(u.y), sca.z, sha.z));            \
    m[3] = fmaxf(m[3], fmaf(bf16hi(u.y), sca.w, sha.w));            \
    m[4] = fmaxf(m[4], fmaf(bf16lo(u.z), scb.x, shb.x));            \
    m[5] = fmaxf(m[5], fmaf(bf16hi(u.z), scb.y, shb.y));            \
    m[6] = fmaxf(m[6], fmaf(bf16lo(u.w), scb.z, shb.z));            \
    m[7] = fmaxf(m[7], fmaf(bf16hi(u.w), scb.w, shb.w));

  int e = s0 + half;
  for (; e + 6 < s1; e += 8){
    const uint4 ua = *(const uint4*)(X2h + (long)esrc[e] * 128 + li * 4);
    const uint4 ub = *(const uint4*)(X2h + (long)esrc[e + 2] * 128 + li * 4);
    const uint4 uc = *(const uint4*)(X2h + (long)esrc[e + 4] * 128 + li * 4);
    const uint4 ud = *(const uint4*)(X2h + (long)esrc[e + 6] * 128 + li * 4);
    ACC8(ua); ACC8(ub); ACC8(uc); ACC8(ud);
  }
  for (; e < s1; e += 2){
    const uint4 u = *(const uint4*)(X2h + (long)esrc[e] * 128 + li * 4);
    ACC8(u);
  }
  #undef ACC8
  #pragma unroll
  for (int j = 0; j < 8; j++) m[j] = fmaxf(m[j], __shfl_xor(m[j], 32));
  if (half == 0){
    uint4 o;
    if (s1 == s0){ o.x = 0u; o.y = 0u; o.z = 0u; o.w = 0u; }
    else {
      o.x = pack_bf16_rne(m[0], m[1]);
      o.y = pack_bf16_rne(m[2], m[3]);
      o.z = pack_bf16_rne(m[4], m[5]);
      o.w = pack_bf16_rne(m[6], m[7]);
    }
    *(uint4*)(X2agg + (long)wid * 128 + li * 4) = o;
  }
}

// ---------------- GEMM: C[M,NT] = [Alo|Ahi][M,KT] * B[NT,KT]^T (+bias) --------
// r15-proven: 128x128 tile, 4 waves, BK=64, SINGLE 32KB buffer,
// __syncthreads() full drains (race-safe), __launch_bounds__(256,4),
// XCD-swizzled 1D grid, 3-bit XOR swizzle both-sides.
template<int KT, bool EPI1>
__global__ __launch_bounds__(256, 4)
void k_gemm(const uint16_t* __restrict__ Alo, const uint16_t* __restrict__ Ahi,
            const uint16_t* __restrict__ B, const float* __restrict__ bias,
            uint16_t* __restrict__ outb, float* __restrict__ outf,
            float* __restrict__ sum, float* __restrict__ sumsq)
{
  constexpr int NSTEPS = KT / 64;
  constexpr int HSTEPS = NSTEPS / 2;
  constexpr int NT = EPI1 ? 256 : 512;
  constexpr int NW = NT / 128;                 // nblk count (2 or 4)
  constexpr int WG = 782 * NW;                 // real workgroups
  constexpr int PER = (WG + 7) / 8;            // wgids per XCD (grid padded to PER*8)
  __shared__ uint8_t lds[32768];               // A 16K | B 16K (single buffer)
  const int bid = blockIdx.x;
  const int wgid = (bid & 7) * PER + (bid >> 3);
  if (wgid >= WG) return;
  const int mblk = wgid / NW, nblk = wgid % NW;
  const int tid = threadIdx.x, lane = tid & 63, wv = tid >> 6;
  const int wvm = wv >> 1, wvn = wv & 1;

  f32x4 acc[4][4] = {};

  const int srow = wv * 32 + (lane >> 3);   // + i*8
  const int skb  = (lane & 7) * 16;

  // per-lane global source addresses (row-clamped A); A halves: row stride KT bytes
  const uint8_t* asrc_lo[4];
  const uint8_t* asrc_hi[4];
  const uint8_t* bsrc[4];
  #pragma unroll
  for (int i = 0; i < 4; i++){
    int row = srow + i * 8;
    int kbsw = skb ^ ((row & 7) << 4);
    long grow = (long)mblk * 128 + row;
    if (grow > N_NODES - 1) grow = N_NODES - 1;
    asrc_lo[i] = (const uint8_t*)Alo + grow * KT + kbsw;
    asrc_hi[i] = (const uint8_t*)Ahi + grow * KT + kbsw;
    bsrc[i] = (const uint8_t*)B + ((long)nblk * 128 + row) * (KT * 2) + kbsw;
  }

  #define STAGE(ks)                                                          \
    _Pragma("unroll")                                                        \
    for (int i = 0; i < 4; i++)                                              \
      gl2lds16((ks) < HSTEPS ? asrc_lo[i] + (long)(ks) * 128                 \
                             : asrc_hi[i] + (long)((ks) - HSTEPS) * 128,     \
               &lds[(wv * 4 + i) * 1024]);                                   \
    _Pragma("unroll")                                                        \
    for (int i = 0; i < 4; i++)                                              \
      gl2lds16(bsrc[i] + (long)(ks) * 128,                                   \
               &lds[16384 + (wv * 4 + i) * 1024]);

  #pragma unroll
  for (int ks = 0; ks < NSTEPS; ++ks){
    if (ks) __syncthreads();   // full drain: all waves' LDS reads complete
    STAGE(ks);
    __syncthreads();           // full drain: vmcnt(0) -> staged data landed

    const uint8_t* ldsA = &lds[0];
    const uint8_t* ldsB = &lds[16384];
    #pragma unroll
    for (int kk = 0; kk < 2; kk++){
      const int kb = kk * 64 + (lane >> 4) * 16;
      bf16x8 af[4], bfr[4];
      #pragma unroll
      for (int m = 0; m < 4; m++){
        int row = wvm * 64 + m * 16 + (lane & 15);
        af[m] = *(const bf16x8*)(ldsA + row * 128 + (kb ^ ((row & 7) << 4)));
      }
      #pragma unroll
      for (int n = 0; n < 4; n++){
        int row = wvn * 64 + n * 16 + (lane & 15);
        bfr[n] = *(const bf16x8*)(ldsB + row * 128 + (kb ^ ((row & 7) << 4)));
      }
      #pragma unroll
      for (int m = 0; m < 4; m++)
        #pragma unroll
        for (int n = 0; n < 4; n++)
          acc[m][n] = __builtin_amdgcn_mfma_f32_16x16x32_bf16(af[m], bfr[n], acc[m][n], 0, 0, 0);
    }
  }
  #undef STAGE

  // epilogue
  const int rgrp = (lane >> 4) * 4;
  #pragma unroll
  for (int n = 0; n < 4; n++){
    const int col = nblk * 128 + wvn * 64 + n * 16 + (lane & 15);
    const float bv = bias[col];
    float s1v = 0.f, s2v = 0.f;
    #pragma unroll
    for (int m = 0; m < 4; m++){
      const int rowb = mblk * 128 + wvm * 64 + m * 16 + rgrp;
      f32x4 v = acc[m][n];
      #pragma unroll
      for (int j = 0; j < 4; j++){
        const int row = rowb + j;
        const float h = v[j] + bv;
        if (row < N_NODES){
          if (EPI1){
            outb[(long)row * NT + col] = f32_to_bf16(h);
            s1v += h; s2v += h * h;
          } else {
            __builtin_nontemporal_store(h, &outf[(long)row * NT + col]);
          }
        }
      }
    }
    if (EPI1){
      s1v += __shfl_xor(s1v, 16); s1v += __shfl_xor(s1v, 32);
      s2v += __shfl_xor(s2v, 16); s2v += __shfl_xor(s2v, 32);
      if (lane < 16){
        atomicAdd(&sum[col], s1v);
        atomicAdd(&sumsq[col], s2v);
      }
    }
  }
}

extern "C" void kernel_launch(void* const* d_in, const int* in_sizes, int n_in,
                              void* d_out, int out_size, void* d_ws, size_t ws_size,
                              hipStream_t stream){
  const float* x     = (const float*)d_in[0];
  const int*   ei    = (const int*)d_in[1];
  const float* W1l   = (const float*)d_in[2];
  const float* b1    = (const float*)d_in[3];
  const float* W1r   = (const float*)d_in[4];
  const float* gamma = (const float*)d_in[5];
  const float* beta  = (const float*)d_in[6];
  const float* W2l   = (const float*)d_in[7];
  const float* b2    = (const float*)d_in[8];
  const float* W2r   = (const float*)d_in[9];
  const int* esrc_in = ei;            // row 0 = src
  const int* edst_in = ei + N_EDGES;  // row 1 = dst

  uint8_t* ws = (uint8_t*)d_ws;
  uint16_t* X1agg    = (uint16_t*)(ws + 0);           // [N][128] bf16 agg1   25,600,000
  uint16_t* X1x      = (uint16_t*)(ws + 25600000);    // [N][128] bf16 x      25,600,000
  uint16_t* X2agg    = (uint16_t*)(ws + 51200000);    // [N][256] bf16 agg2   51,200,000
  uint16_t* X2h      = (uint16_t*)(ws + 102400000);   // [N][256] bf16 h_pre  51,200,000
  int* ebuk          = (int*)(ws + 51200000);         // aliases X2agg (CSR done before agg2)
  int* esrc          = (int*)(ws + 153600000);        // 6,400,000
  int* row_start     = (int*)(ws + 160000000);        // 400,128
  int* gcur          = (int*)(ws + 160402176);        // 1,564 (bucket cursors, 391)
  uint16_t* W1cat    = (uint16_t*)(ws + 160800256);   // 131,072
  uint16_t* W2cat    = (uint16_t*)(ws + 160931328);   // 524,288
  float* bias2       = (float*)(ws + 161455616);      // 2,048
  float* sum         = (float*)(ws + 161457664);      // 1,024
  float* sumsq       = (float*)(ws + 161458688);      // 1,024

  // pre: convx (12500) + init (1) + w1 (256)
  hipLaunchKernelGGL(k_pre, dim3(12757), dim3(256), 0, stream,
                     x, X1x, gcur, sum, sumsq, W1l, W1r, W1cat);
  hipLaunchKernelGGL(k_bucket, dim3(N_EDGES / EPB + 1), dim3(256), 0, stream,
                     esrc_in, edst_in, gcur, ebuk);
  hipLaunchKernelGGL(k_fillc, dim3(NBUK), dim3(256), 0, stream,
                     gcur, ebuk, row_start, esrc);
  hipLaunchKernelGGL(k_agg1, dim3(25000), dim3(256), 0, stream,
                     (const uint32_t*)X1x, row_start, esrc, (uint32_t*)X1agg);

  // gemm1: WG=1564 -> grid 1568 (196 per XCD)
  hipLaunchKernelGGL((k_gemm<256, true>), dim3(1568), dim3(256), 0, stream,
                     X1agg, X1x, W1cat, b1, X2h, (float*)nullptr, sum, sumsq);

  // agg2 (25000) + w2 fold (128)
  hipLaunchKernelGGL(k_aggw2, dim3(25128), dim3(256), 0, stream,
                     (const uint32_t*)X2h, row_start, esrc, sum, sumsq, gamma, beta,
                     (uint32_t*)X2agg, W2l, W2r, b2, W2cat, bias2);

  // gemm2: WG=3128 -> grid 3128 (391 per XCD)
  hipLaunchKernelGGL((k_gemm<512, false>), dim3(3128), dim3(256), 0, stream,
                     X2agg, X2h, W2cat, bias2, (uint16_t*)nullptr, (float*)d_out,
                     (float*)nullptr, (float*)nullptr);
}